// Round 4
// baseline (238.231 us; speedup 1.0000x reference)
//
#include <hip/hip_runtime.h>

// Problem constants (match reference setup_inputs)
constexpr int       kM = 50000;      // pillars
constexpr long long kL = 2000000;    // pairs
constexpr int       kRowLen = 70;    // C + 6

// Output layout (all float32, concatenated flat in return order):
//   [0, 150000)                pillar_indices (int -> float)
//   [150000, 2150000)          pillar_set_indices (int -> float)
//   [2150000, 142150000)       group_features (L x 70) row-major
//   [142150000]                indice2bev = 1.0f
constexpr long long kOutPillarIdx = 0;
constexpr long long kOutPsi       = 150000;
constexpr long long kOutGF        = 2150000;
constexpr long long kOutBev       = 142150000;

constexpr int kRowsPerWave = 16;
constexpr int kWaves       = 4;
constexpr int kTileRows    = kRowsPerWave * kWaves;       // 64
constexpr int kGrid        = (int)(kL / kTileRows);       // 31250
constexpr int kPillarIdx4  = kM * 3 / 4;                  // 37500 int4

// LDS-free fused kernel. Per wave (16 rows):
//   0) ONE coalesced load instruction fetches 16 point-idx (lanes 0-15)
//      and 16 pillar-idx (lanes 16-31); __shfl distributes.
//   1) Features: 16 lanes x float4 gather per row, stored DIRECTLY to
//      global as two float2s (row stride 280 B is 8-aligned; L2
//      write-combines into full lines).
//   2) Coords: lanes 0-47 compute absl/rel for (row, c) with scalar
//      loads from L2-resident xyz/pc tables, scalar stores.
// Chain is gather->store (2 levels) vs previous 5-level LDS pipeline.
__global__ __launch_bounds__(256, 8)
void pillar_group_fused_kernel(const float* __restrict__ xyz,
                               const float4* __restrict__ pf4,   // (N,16) float4
                               const float* __restrict__ pc,
                               const int4*  __restrict__ pillar_idx4,
                               const int4*  __restrict__ psi4,
                               const int*   __restrict__ point_set_idx,
                               const int*   __restrict__ pillar_set_idx,
                               float* __restrict__ out) {
    const int tid  = threadIdx.x;
    const int wave = tid >> 6;
    const int lane = tid & 63;
    const int row0 = blockIdx.x * kTileRows + wave * kRowsPerWave;

    // ---- Side outputs (fused to avoid extra graph dispatches) ----
    if (tid < 16) {
        // pillar_set_indices -> float, 16 float4 per block (covers L exactly)
        int k = blockIdx.x * 16 + tid;
        int4 v = psi4[k];
        ((float4*)(out + kOutPsi))[k] =
            make_float4((float)v.x, (float)v.y, (float)v.z, (float)v.w);
    } else if (tid == 16) {
        int k = blockIdx.x;
        if (k < kPillarIdx4) {
            int4 v = pillar_idx4[k];
            ((float4*)(out + kOutPillarIdx))[k] =
                make_float4((float)v.x, (float)v.y, (float)v.z, (float)v.w);
        }
    } else if (tid == 17) {
        int k = kGrid + blockIdx.x;
        if (k < kPillarIdx4) {
            int4 v = pillar_idx4[k];
            ((float4*)(out + kOutPillarIdx))[k] =
                make_float4((float)v.x, (float)v.y, (float)v.z, (float)v.w);
        }
    } else if (tid == 18 && blockIdx.x == 0) {
        out[kOutBev] = 1.0f;
    }

    // ---- Index preload: one coalesced load, lanes 0-15 / 16-31 ----
    int idxv = 0;
    if (lane < 16)       idxv = point_set_idx[row0 + lane];
    else if (lane < 32)  idxv = pillar_set_idx[row0 + lane - 16];

    float* gf = out + kOutGF;

    // ---- Phase 1: point features, direct gather->store ----
    {
        const int j    = lane & 15;   // float4 chunk within row
        const int rsub = lane >> 4;   // 0..3
        #pragma unroll
        for (int it = 0; it < 4; ++it) {
            const int r = it * 4 + rsub;
            const int p = __shfl(idxv, r);
            const float4 v = pf4[(long long)p * 16 + j];
            float* dst = gf + (long long)(row0 + r) * kRowLen + j * 4; // 8B-al
            *(float2*)(dst)     = make_float2(v.x, v.y);
            *(float2*)(dst + 2) = make_float2(v.z, v.w);
        }
    }

    // ---- Phase 2: absolute + relative coords (lanes 0-47) ----
    if (lane < kRowsPerWave * 3) {
        const int r = lane / 3;        // 0..15
        const int c = lane - r * 3;    // 0..2
        const int p = __shfl(idxv, r);
        const int q = __shfl(idxv, 16 + r);
        const float x   = xyz[(long long)p * 3 + c];
        const float pcv = pc[(long long)q * 3 + c];
        const float off = (c == 0) ? 0.0f : ((c == 1) ? -40.0f : -3.0f);
        float* rowp = gf + (long long)(row0 + r) * kRowLen;
        rowp[64 + c] = x + off;   // absolute
        rowp[67 + c] = x - pcv;   // relative
    }
}

extern "C" void kernel_launch(void* const* d_in, const int* in_sizes, int n_in,
                              void* d_out, int out_size, void* d_ws, size_t ws_size,
                              hipStream_t stream) {
    const float* xyz             = (const float*)d_in[0]; // (N,3)
    const float* point_features  = (const float*)d_in[1]; // (N,C)
    const float* pillar_centers  = (const float*)d_in[2]; // (M,3)
    const int*   pillar_indices  = (const int*)d_in[3];   // (M,3)
    const int*   point_set_idx   = (const int*)d_in[4];   // (L,)
    const int*   pillar_set_idx  = (const int*)d_in[5];   // (L,)

    float* out = (float*)d_out;

    pillar_group_fused_kernel<<<kGrid, 256, 0, stream>>>(
        xyz, (const float4*)point_features, pillar_centers,
        (const int4*)pillar_indices, (const int4*)pillar_set_idx,
        point_set_idx, pillar_set_idx, out);
}

// Round 5
// 197.811 us; speedup vs baseline: 1.2043x; 1.2043x over previous
//
#include <hip/hip_runtime.h>

// Problem constants (match reference setup_inputs)
constexpr int       kM = 50000;      // pillars
constexpr long long kL = 2000000;    // pairs
constexpr int       kRowLen = 70;    // C + 6

// Output layout (all float32, concatenated flat in return order):
//   [0, 150000)                pillar_indices (int -> float)
//   [150000, 2150000)          pillar_set_indices (int -> float)
//   [2150000, 142150000)       group_features (L x 70) row-major
//   [142150000]                indice2bev = 1.0f
constexpr long long kOutPillarIdx = 0;
constexpr long long kOutPsi       = 150000;
constexpr long long kOutGF        = 2150000;
constexpr long long kOutBev       = 142150000;

constexpr int kRowsPerWave = 16;
constexpr int kWaves       = 4;
constexpr int kTileRows    = kRowsPerWave * kWaves;       // 64
constexpr int kGrid        = (int)(kL / kTileRows);       // 31250
constexpr int kPillarIdx4  = kM * 3 / 4;                  // 37500 int4

// Per-wave LDS: region A = 16 rows x 64 feats (256B stride, DMA-friendly),
// region B = 16 rows x 6 coords (24B). 4480 B per wave, 17920 B per block.
constexpr int kAFloats    = kRowsPerWave * 64;            // 1024
constexpr int kBFloats    = kRowsPerWave * 6;             // 96
constexpr int kWaveFloats = kAFloats + kBFloats;          // 1120

// Async global->LDS DMA, 16 B per lane. Global address is per-lane
// (gathered); LDS dest is wave-uniform base, HW writes base + lane*16.
__device__ __forceinline__ void gload_lds16(const void* g, void* l) {
    __builtin_amdgcn_global_load_lds(
        (__attribute__((address_space(1))) void*)g,
        (__attribute__((address_space(3))) void*)l,
        16, 0, 0);
}

__global__ __launch_bounds__(256, 8)
void pillar_group_fused_kernel(const float* __restrict__ xyz,
                               const float4* __restrict__ pf4,   // (N,16) float4
                               const float* __restrict__ pc,
                               const int4*  __restrict__ pillar_idx4,
                               const int4*  __restrict__ psi4,
                               const int*   __restrict__ point_set_idx,
                               const int*   __restrict__ pillar_set_idx,
                               float* __restrict__ out) {
    __shared__ float s[kWaves * kWaveFloats];  // 17920 B

    const int tid  = threadIdx.x;
    const int wave = tid >> 6;
    const int lane = tid & 63;
    const int row0 = blockIdx.x * kTileRows + wave * kRowsPerWave;
    float* sA = &s[wave * kWaveFloats];   // features, 16 x 256 B
    float* sB = sA + kAFloats;            // coords,   16 x 24 B

    // ---- Index preload: one coalesced load, lanes 0-15 / 16-31 ----
    int idxv = 0;
    if (lane < 16)       idxv = point_set_idx[row0 + lane];
    else if (lane < 32)  idxv = pillar_set_idx[row0 + lane - 16];

    // ---- Phase A: 4 async DMA instructions cover all 16 rows ----
    // it-th DMA: rows it*4..it*4+3, dest 1 KB at sA + it*256 floats;
    // lane = rsub*16 + j lands at byte rsub*256 + j*16 == A[r][j]. 
    {
        const int j    = lane & 15;
        const int rsub = lane >> 4;
        #pragma unroll
        for (int it = 0; it < 4; ++it) {
            const int r = it * 4 + rsub;
            const int p = __shfl(idxv, r);
            gload_lds16(&pf4[(long long)p * 16 + j], sA + it * 256);
        }
    }

    // ---- Side outputs (overlap with DMA flight) ----
    if (tid < 16) {
        int k = blockIdx.x * 16 + tid;   // covers L/4 exactly
        int4 v = psi4[k];
        ((float4*)(out + kOutPsi))[k] =
            make_float4((float)v.x, (float)v.y, (float)v.z, (float)v.w);
    } else if (tid == 16) {
        int k = blockIdx.x;
        if (k < kPillarIdx4) {
            int4 v = pillar_idx4[k];
            ((float4*)(out + kOutPillarIdx))[k] =
                make_float4((float)v.x, (float)v.y, (float)v.z, (float)v.w);
        }
    } else if (tid == 17) {
        int k = kGrid + blockIdx.x;
        if (k < kPillarIdx4) {
            int4 v = pillar_idx4[k];
            ((float4*)(out + kOutPillarIdx))[k] =
                make_float4((float)v.x, (float)v.y, (float)v.z, (float)v.w);
        }
    } else if (tid == 18 && blockIdx.x == 0) {
        out[kOutBev] = 1.0f;
    }

    // ---- Phase B: absolute + relative coords (lanes 0-47) ----
    if (lane < kRowsPerWave * 3) {
        const int r = lane / 3;        // 0..15
        const int c = lane - r * 3;    // 0..2
        const int p = __shfl(idxv, r);
        const int q = __shfl(idxv, 16 + r);
        const float x   = xyz[(long long)p * 3 + c];
        const float pcv = pc[(long long)q * 3 + c];
        const float off = (c == 0) ? 0.0f : ((c == 1) ? -40.0f : -3.0f);
        sB[r * 6 + c]     = x + off;   // absolute
        sB[r * 6 + 3 + c] = x - pcv;   // relative
    }

    // ---- Drain DMA before reading region A (rule #18 fence) ----
    asm volatile("s_waitcnt vmcnt(0)" ::: "memory");
    __builtin_amdgcn_sched_barrier(0);

    // ---- Phase C: stitch 280 float4s per wave from A/B, aligned stores ----
    // Byte b within the wave tile: row = b/280, off = b%280; off<256 -> A,
    // else -> B. Every 8 B granule is intra-region (280 % 8 == 0).
    {
        const float2* A2 = (const float2*)sA;   // 512 float2
        const float2* B2 = (const float2*)sB;   // 48 float2
        float4* o4 = (float4*)(out + kOutGF + (long long)row0 * kRowLen);
        #pragma unroll
        for (int it = 0; it < 5; ++it) {
            const int k = it * 64 + lane;
            if (k < kRowsPerWave * kRowLen / 4) {   // 280
                const unsigned b0 = (unsigned)k * 16u;
                const unsigned b1 = b0 + 8u;
                const unsigned r0 = b0 / 280u, o0 = b0 - r0 * 280u;
                const unsigned r1 = b1 / 280u, o1 = b1 - r1 * 280u;
                const float2 g0 = (o0 < 256u) ? A2[r0 * 32 + (o0 >> 3)]
                                              : B2[r0 * 3 + ((o0 - 256u) >> 3)];
                const float2 g1 = (o1 < 256u) ? A2[r1 * 32 + (o1 >> 3)]
                                              : B2[r1 * 3 + ((o1 - 256u) >> 3)];
                o4[k] = make_float4(g0.x, g0.y, g1.x, g1.y);
            }
        }
    }
}

extern "C" void kernel_launch(void* const* d_in, const int* in_sizes, int n_in,
                              void* d_out, int out_size, void* d_ws, size_t ws_size,
                              hipStream_t stream) {
    const float* xyz             = (const float*)d_in[0]; // (N,3)
    const float* point_features  = (const float*)d_in[1]; // (N,C)
    const float* pillar_centers  = (const float*)d_in[2]; // (M,3)
    const int*   pillar_indices  = (const int*)d_in[3];   // (M,3)
    const int*   point_set_idx   = (const int*)d_in[4];   // (L,)
    const int*   pillar_set_idx  = (const int*)d_in[5];   // (L,)

    float* out = (float*)d_out;

    pillar_group_fused_kernel<<<kGrid, 256, 0, stream>>>(
        xyz, (const float4*)point_features, pillar_centers,
        (const int4*)pillar_indices, (const int4*)pillar_set_idx,
        point_set_idx, pillar_set_idx, out);
}

// Round 7
// 192.229 us; speedup vs baseline: 1.2393x; 1.0290x over previous
//
#include <hip/hip_runtime.h>

// Problem constants (match reference setup_inputs)
constexpr int       kM = 50000;      // pillars
constexpr long long kL = 2000000;    // pairs
constexpr int       kRowLen = 70;    // C + 6

// Output layout (all float32, concatenated flat in return order):
//   [0, 150000)                pillar_indices (int -> float)
//   [150000, 2150000)          pillar_set_indices (int -> float)
//   [2150000, 142150000)       group_features (L x 70) row-major
//   [142150000]                indice2bev = 1.0f
constexpr long long kOutPillarIdx = 0;
constexpr long long kOutPsi       = 150000;
constexpr long long kOutGF        = 2150000;
constexpr long long kOutBev       = 142150000;

constexpr int kRowsPerWave = 16;
constexpr int kWaves       = 4;
constexpr int kTileRows    = kRowsPerWave * kWaves;       // 64
constexpr int kGrid        = (int)(kL / kTileRows);       // 31250
constexpr int kPillarIdx4  = kM * 3 / 4;                  // 37500 int4

// Per-wave LDS: region A = 16 rows x 64 feats (256B stride, DMA-friendly),
// region B = 16 rows x 6 coords (24B). 4480 B per wave, 17920 B per block.
constexpr int kAFloats    = kRowsPerWave * 64;            // 1024
constexpr int kBFloats    = kRowsPerWave * 6;             // 96
constexpr int kWaveFloats = kAFloats + kBFloats;          // 1120

// clang-native vector types (HIP_vector_type is a struct -> nontemporal
// builtins reject it; ext_vector_type is accepted).
typedef float f32x4 __attribute__((ext_vector_type(4)));
typedef float f32x2 __attribute__((ext_vector_type(2)));
typedef int   i32x4 __attribute__((ext_vector_type(4)));

// Async global->LDS DMA, 16 B per lane. Global address is per-lane
// (gathered); LDS dest is wave-uniform base, HW writes base + lane*16.
__device__ __forceinline__ void gload_lds16(const void* g, void* l) {
    __builtin_amdgcn_global_load_lds(
        (__attribute__((address_space(1))) void*)g,
        (__attribute__((address_space(3))) void*)l,
        16, 0, 0);
}

__global__ __launch_bounds__(256, 8)
void pillar_group_fused_kernel(const float* __restrict__ xyz,
                               const f32x4* __restrict__ pf4,   // (N,16) f32x4
                               const float* __restrict__ pc,
                               const i32x4* __restrict__ pillar_idx4,
                               const i32x4* __restrict__ psi4,
                               const int*   __restrict__ point_set_idx,
                               const int*   __restrict__ pillar_set_idx,
                               float* __restrict__ out) {
    __shared__ float s[kWaves * kWaveFloats];  // 17920 B

    const int tid  = threadIdx.x;
    const int wave = tid >> 6;
    const int lane = tid & 63;
    const int row0 = blockIdx.x * kTileRows + wave * kRowsPerWave;
    float* sA = &s[wave * kWaveFloats];   // features, 16 x 256 B
    float* sB = sA + kAFloats;            // coords,   16 x 24 B

    // ---- Index preload: one coalesced load, lanes 0-15 / 16-31 ----
    // Read-once streams: non-temporal to avoid polluting L2/L3.
    int idxv = 0;
    if (lane < 16)       idxv = __builtin_nontemporal_load(&point_set_idx[row0 + lane]);
    else if (lane < 32)  idxv = __builtin_nontemporal_load(&pillar_set_idx[row0 + lane - 16]);

    // ---- Phase A: 4 async DMA instructions cover all 16 rows ----
    {
        const int j    = lane & 15;
        const int rsub = lane >> 4;
        #pragma unroll
        for (int it = 0; it < 4; ++it) {
            const int r = it * 4 + rsub;
            const int p = __shfl(idxv, r);
            gload_lds16(&pf4[(long long)p * 16 + j], sA + it * 256);
        }
    }

    // ---- Side outputs (overlap with DMA flight), nt loads/stores ----
    if (tid < 16) {
        int k = blockIdx.x * 16 + tid;   // covers L/4 exactly
        i32x4 v = __builtin_nontemporal_load(&psi4[k]);
        f32x4 o = {(float)v.x, (float)v.y, (float)v.z, (float)v.w};
        __builtin_nontemporal_store(o, (f32x4*)(out + kOutPsi) + k);
    } else if (tid == 16) {
        int k = blockIdx.x;
        if (k < kPillarIdx4) {
            i32x4 v = __builtin_nontemporal_load(&pillar_idx4[k]);
            f32x4 o = {(float)v.x, (float)v.y, (float)v.z, (float)v.w};
            __builtin_nontemporal_store(o, (f32x4*)(out + kOutPillarIdx) + k);
        }
    } else if (tid == 17) {
        int k = kGrid + blockIdx.x;
        if (k < kPillarIdx4) {
            i32x4 v = __builtin_nontemporal_load(&pillar_idx4[k]);
            f32x4 o = {(float)v.x, (float)v.y, (float)v.z, (float)v.w};
            __builtin_nontemporal_store(o, (f32x4*)(out + kOutPillarIdx) + k);
        }
    } else if (tid == 18 && blockIdx.x == 0) {
        __builtin_nontemporal_store(1.0f, &out[kOutBev]);
    }

    // ---- Phase B: absolute + relative coords (lanes 0-47) ----
    if (lane < kRowsPerWave * 3) {
        const int r = lane / 3;        // 0..15
        const int c = lane - r * 3;    // 0..2
        const int p = __shfl(idxv, r);
        const int q = __shfl(idxv, 16 + r);
        const float x   = xyz[(long long)p * 3 + c];
        const float pcv = pc[(long long)q * 3 + c];
        const float off = (c == 0) ? 0.0f : ((c == 1) ? -40.0f : -3.0f);
        sB[r * 6 + c]     = x + off;   // absolute
        sB[r * 6 + 3 + c] = x - pcv;   // relative
    }

    // ---- Drain DMA before reading region A (rule #18 fence) ----
    asm volatile("s_waitcnt vmcnt(0)" ::: "memory");
    __builtin_amdgcn_sched_barrier(0);

    // ---- Phase C: stitch 280 float4s per wave from A/B, NT stores ----
    // Byte b within the wave tile: row = b/280, off = b%280; off<256 -> A,
    // else -> B. Every 8 B granule is intra-region (280 % 8 == 0).
    {
        const f32x2* A2 = (const f32x2*)sA;   // 512 f32x2
        const f32x2* B2 = (const f32x2*)sB;   // 48 f32x2
        f32x4* o4 = (f32x4*)(out + kOutGF + (long long)row0 * kRowLen);
        #pragma unroll
        for (int it = 0; it < 5; ++it) {
            const int k = it * 64 + lane;
            if (k < kRowsPerWave * kRowLen / 4) {   // 280
                const unsigned b0 = (unsigned)k * 16u;
                const unsigned b1 = b0 + 8u;
                const unsigned r0 = b0 / 280u, o0 = b0 - r0 * 280u;
                const unsigned r1 = b1 / 280u, o1 = b1 - r1 * 280u;
                const f32x2 g0 = (o0 < 256u) ? A2[r0 * 32 + (o0 >> 3)]
                                             : B2[r0 * 3 + ((o0 - 256u) >> 3)];
                const f32x2 g1 = (o1 < 256u) ? A2[r1 * 32 + (o1 >> 3)]
                                             : B2[r1 * 3 + ((o1 - 256u) >> 3)];
                f32x4 o = {g0.x, g0.y, g1.x, g1.y};
                __builtin_nontemporal_store(o, &o4[k]);
            }
        }
    }
}

extern "C" void kernel_launch(void* const* d_in, const int* in_sizes, int n_in,
                              void* d_out, int out_size, void* d_ws, size_t ws_size,
                              hipStream_t stream) {
    const float* xyz             = (const float*)d_in[0]; // (N,3)
    const float* point_features  = (const float*)d_in[1]; // (N,C)
    const float* pillar_centers  = (const float*)d_in[2]; // (M,3)
    const int*   pillar_indices  = (const int*)d_in[3];   // (M,3)
    const int*   point_set_idx   = (const int*)d_in[4];   // (L,)
    const int*   pillar_set_idx  = (const int*)d_in[5];   // (L,)

    float* out = (float*)d_out;

    pillar_group_fused_kernel<<<kGrid, 256, 0, stream>>>(
        xyz, (const f32x4*)point_features, pillar_centers,
        (const i32x4*)pillar_indices, (const i32x4*)pillar_set_idx,
        point_set_idx, pillar_set_idx, out);
}